// Round 4
// baseline (4330.178 us; speedup 1.0000x reference)
//
#include <hip/hip_runtime.h>

typedef __attribute__((ext_vector_type(8))) short short8;
typedef __attribute__((ext_vector_type(4))) float floatx4;

#define N_PF 60000
#define N_GW 300000
#define N_SW 60000
#define EPT 1000000          // edges per (non-self) edge type
#define L_CNT 1140000        // concat of 7 per-dst count arrays
#define NBLK 1114            // ceil(L_CNT/1024)
#define SRC_MASK 0x7FFFFFF   // low 27 bits = src id; bits 27+ = dst & 15

__device__ __forceinline__ unsigned short f2bf(float f) {
  unsigned u = __float_as_uint(f);
  u = (u + 0x7FFF + ((u >> 16) & 1)) >> 16;
  return (unsigned short)u;
}
__device__ __forceinline__ float bf2f(unsigned short u) {
  return __uint_as_float((unsigned)u << 16);
}

__device__ __forceinline__ int cnt_base(int et) {
  switch (et) {
    case 0: return 0;
    case 1: return 300000;
    case 2: return 360000;
    case 3: return 420000;
    case 4: return 480000;
    case 5: return 780000;
    default: return 840000;
  }
}

// ---------------- input cast f32 -> bf16 ----------------
__global__ __launch_bounds__(256) void k_cast(const float4* __restrict__ x,
                                              ushort4* __restrict__ xb, int n4) {
  int i = blockIdx.x * 256 + threadIdx.x;
  if (i < n4) {
    float4 v = x[i];
    ushort4 o;
    o.x = f2bf(v.x); o.y = f2bf(v.y); o.z = f2bf(v.z); o.w = f2bf(v.w);
    xb[i] = o;
  }
}

// ---------------- CSR build ----------------
__global__ __launch_bounds__(256) void k_count(
    const int* e0, const int* e1, const int* e2, const int* e3,
    const int* e4, const int* e5, const int* e6, int* __restrict__ cnt,
    int* __restrict__ loc) {
  int gid = blockIdx.x * 256 + threadIdx.x;
  if (gid >= 7 * EPT) return;
  int et = gid / EPT;
  int i = gid - et * EPT;
  const int* ei;
  switch (et) {
    case 0: ei = e0; break; case 1: ei = e1; break; case 2: ei = e2; break;
    case 3: ei = e3; break; case 4: ei = e4; break; case 5: ei = e5; break;
    default: ei = e6; break;
  }
  int dst = ei[EPT + i];
  loc[gid] = atomicAdd(&cnt[cnt_base(et) + dst], 1);
}

__global__ __launch_bounds__(256) void k_scan1(const int* __restrict__ cnt,
                                               int* __restrict__ bsum) {
  __shared__ int sh[4];
  int base = blockIdx.x * 1024 + threadIdx.x * 4;
  int s = 0;
#pragma unroll
  for (int u = 0; u < 4; ++u) { int i = base + u; if (i < L_CNT) s += cnt[i]; }
  for (int off = 1; off < 64; off <<= 1) s += __shfl_xor(s, off, 64);
  int lane = threadIdx.x & 63, w = threadIdx.x >> 6;
  if (lane == 0) sh[w] = s;
  __syncthreads();
  if (threadIdx.x == 0) bsum[blockIdx.x] = sh[0] + sh[1] + sh[2] + sh[3];
}

__global__ __launch_bounds__(256) void k_scan2(const int* __restrict__ bsum,
                                               int* __restrict__ bpre) {
  __shared__ int sh[256];
  int carry = 0;
  for (int base = 0; base < NBLK; base += 256) {
    int idx = base + threadIdx.x;
    int v = (idx < NBLK) ? bsum[idx] : 0;
    sh[threadIdx.x] = v;
    __syncthreads();
    for (int off = 1; off < 256; off <<= 1) {
      int t = (threadIdx.x >= off) ? sh[threadIdx.x - off] : 0;
      __syncthreads();
      sh[threadIdx.x] += t;
      __syncthreads();
    }
    if (idx < NBLK) bpre[idx] = carry + sh[threadIdx.x] - v;  // exclusive
    carry += sh[255];
    __syncthreads();
  }
}

__global__ __launch_bounds__(256) void k_scan3(const int* __restrict__ cnt,
                                               const int* __restrict__ bpre,
                                               int* __restrict__ Sarr) {
  __shared__ int wt[4];
  int lane = threadIdx.x & 63, w = threadIdx.x >> 6;
  int base = blockIdx.x * 1024 + threadIdx.x * 4;
  int v[4]; int ts = 0;
#pragma unroll
  for (int u = 0; u < 4; ++u) {
    int i = base + u;
    v[u] = (i < L_CNT) ? cnt[i] : 0;
    ts += v[u];
  }
  int x = ts;
  for (int off = 1; off < 64; off <<= 1) {
    int t = __shfl_up(x, off, 64);
    if (lane >= off) x += t;
  }
  int wexcl = x - ts;
  if (lane == 63) wt[w] = x;
  __syncthreads();
  int wpre = 0;
#pragma unroll
  for (int u = 0; u < 4; ++u) if (u < w) wpre += wt[u];
  int run = bpre[blockIdx.x] + wpre + wexcl;
#pragma unroll
  for (int u = 0; u < 4; ++u) {
    int i = base + u;
    if (i < L_CNT) Sarr[i] = run;
    run += v[u];
    if (i == L_CNT - 1) Sarr[L_CNT] = run;  // sentinel = total (7M)
  }
}

__global__ __launch_bounds__(256) void k_fill(
    const int* e0, const int* e1, const int* e2, const int* e3,
    const int* e4, const int* e5, const int* e6,
    const int* __restrict__ Sarr, const int* __restrict__ loc,
    int* __restrict__ col) {
  int gid = blockIdx.x * 256 + threadIdx.x;
  if (gid >= 7 * EPT) return;
  int et = gid / EPT;
  int i = gid - et * EPT;
  const int* ei;
  switch (et) {
    case 0: ei = e0; break; case 1: ei = e1; break; case 2: ei = e2; break;
    case 3: ei = e3; break; case 4: ei = e4; break; case 5: ei = e5; break;
    default: ei = e6; break;
  }
  int src = ei[i];
  int dst = ei[EPT + i];
  int pos = Sarr[cnt_base(et) + dst] + loc[gid];
  col[pos] = src | ((dst & 15) << 27);  // pack local tile slot (tiles 16-aligned)
}

// ---------------- weight prep (fold + swizzle -> bf16) ----------------
template <int KIN, int NE>
__global__ __launch_bounds__(256) void k_prep(
    const float* __restrict__ Wl, const float* __restrict__ Wr,
    const float* __restrict__ bl, int e0, int e1, int e2, int es,
    unsigned short* __restrict__ wsw, float* __restrict__ bias) {
  constexpr int KCAT = (NE + 1) * KIN;
  int idx = blockIdx.x * 256 + threadIdx.x;
  if (idx < KCAT * 64) {
    int j = idx & 7, lane = (idx >> 3) & 63, t = idx >> 9;
    int ct = t & 3, kc = t >> 2;
    int k = kc * 32 + ((lane >> 4) << 3) + j;
    int c = ct * 16 + (lane & 15);
    int seg = k / KIN, kk = k - seg * KIN;
    float v;
    if (seg < NE) {
      int e = (seg == 0) ? e0 : (seg == 1) ? e1 : e2;
      v = Wl[((size_t)e * 64 + c) * KIN + kk];
    } else {
      v = Wl[((size_t)es * 64 + c) * KIN + kk] +
          Wr[((size_t)es * 64 + c) * KIN + kk] +
          Wr[((size_t)e0 * 64 + c) * KIN + kk] +
          Wr[((size_t)e1 * 64 + c) * KIN + kk];
      if (NE == 3) v += Wr[((size_t)e2 * 64 + c) * KIN + kk];
    }
    wsw[idx] = f2bf(v);
  } else if (idx < KCAT * 64 + 64) {
    int c = idx - KCAT * 64;
    float v = bl[e0 * 64 + c] + bl[e1 * 64 + c] + bl[es * 64 + c];
    if (NE == 3) v += bl[e2 * 64 + c];
    bias[c] = v;
  }
}

// ------- fused edge-parallel gather(mean) + MFMA + bias + ReLU [+lin] -------
// Per 16-node tile & edge type, the CSR edge range is contiguous: split it
// into G balanced chunks (one per LPR-lane group); accumulate rows into a
// per-wave f32 LDS tile via ds_add_f32 (slot = packed dst&15). All loop
// iterations independent -> deep memory pipelining, no degree divergence.
// OMODE: 0 = store bf16 h, 1 = store f32 h, 2 = fused linear+PReLU -> f32 out
template <int KIN, int NE, int OMODE>
__global__ __launch_bounds__(256) void k_layer(
    const int* __restrict__ Sarr, const int* __restrict__ col,
    const unsigned short* __restrict__ s0, const unsigned short* __restrict__ s1,
    const unsigned short* __restrict__ s2, int b0, int b1, int b2,
    const unsigned short* __restrict__ xD,
    const unsigned short* __restrict__ wsw, const float* __restrict__ bias,
    void* __restrict__ hOut, const float* __restrict__ linW,
    const float* __restrict__ linb, const float* __restrict__ pa, int Ndst) {
  constexpr int KCAT = (NE + 1) * KIN;
  constexpr int KCH = KCAT / 32;
  constexpr int ZSTR = KCAT + 8;
  constexpr int LPR = KIN / 4;   // lanes per feature row (8 or 16)
  constexpr int G = 64 / LPR;    // concurrent edge chunks per wave (8 or 4)
  constexpr int FQ = KIN / 4;    // float4s per facc row
  __shared__ unsigned short z[4 * 16 * ZSTR];
  __shared__ float facc[4 * 16 * KIN];
  __shared__ float ic[4 * 16];
  const int lane = threadIdx.x & 63;
  const int wv = threadIdx.x >> 6;
  unsigned short* zw = &z[wv * 16 * ZSTR];
  float* fa = &facc[wv * 16 * KIN];
  float* icw = &ic[wv * 16];
  const int wid = (blockIdx.x * 256 + threadIdx.x) >> 6;
  const int nw = (gridDim.x * 256) >> 6;
  const unsigned short* srcs[3] = {s0, s1, s2};
  const int bases[3] = {b0, b1, b2};
  const int cl = lane & 15, quad = lane >> 4;
  const int g = lane / LPR;      // chunk/group id
  const int c4 = lane % LPR;     // 4-col chunk within row

  for (int nb = wid * 16; nb < Ndst; nb += nw * 16) {  // Ndst % 16 == 0
    // ---- self rows straight to z (bf16) ----
#pragma unroll
    for (int i0 = 0; i0 < 16; i0 += G) {
      int n = nb + i0 + g;
      *(ushort4*)(&zw[(i0 + g) * ZSTR + NE * KIN + c4 * 4]) =
          *(const ushort4*)(xD + (size_t)n * KIN + c4 * 4);
    }
    // ---- per edge type: flat edge loop with LDS f32 atomic accumulate ----
#pragma unroll
    for (int e = 0; e < NE; ++e) {
      float4 z4 = {0.f, 0.f, 0.f, 0.f};
#pragma unroll
      for (int t = lane; t < 16 * FQ; t += 64) ((float4*)fa)[t] = z4;
      if (lane < 16) {
        int c = Sarr[bases[e] + nb + lane + 1] - Sarr[bases[e] + nb + lane];
        if (c < 1) c = 1;
        icw[lane] = 1.0f / (float)c;
      }
      int sT = Sarr[bases[e] + nb];
      int eT = Sarr[bases[e] + nb + 16];  // sentinel makes this safe at the end
      int tot = eT - sT;
      int chunk = (tot + G - 1) / G;
      int cs = sT + g * chunk;
      int ce = cs + chunk;
      if (ce > eT) ce = eT;
      asm volatile("s_waitcnt lgkmcnt(0)" ::: "memory");  // zeros visible
      int j = cs;
      for (; j + 1 < ce; j += 2) {
        int p0 = col[j], p1 = col[j + 1];
        int sl0 = p0 >> 27, sr0 = p0 & SRC_MASK;
        int sl1 = p1 >> 27, sr1 = p1 & SRC_MASK;
        ushort4 v0 = *(const ushort4*)(srcs[e] + (size_t)sr0 * KIN + c4 * 4);
        ushort4 v1 = *(const ushort4*)(srcs[e] + (size_t)sr1 * KIN + c4 * 4);
        float* f0 = &fa[sl0 * KIN + c4 * 4];
        float* f1 = &fa[sl1 * KIN + c4 * 4];
        atomicAdd(f0 + 0, bf2f(v0.x)); atomicAdd(f0 + 1, bf2f(v0.y));
        atomicAdd(f0 + 2, bf2f(v0.z)); atomicAdd(f0 + 3, bf2f(v0.w));
        atomicAdd(f1 + 0, bf2f(v1.x)); atomicAdd(f1 + 1, bf2f(v1.y));
        atomicAdd(f1 + 2, bf2f(v1.z)); atomicAdd(f1 + 3, bf2f(v1.w));
      }
      if (j < ce) {
        int p0 = col[j];
        int sl0 = p0 >> 27, sr0 = p0 & SRC_MASK;
        ushort4 v0 = *(const ushort4*)(srcs[e] + (size_t)sr0 * KIN + c4 * 4);
        float* f0 = &fa[sl0 * KIN + c4 * 4];
        atomicAdd(f0 + 0, bf2f(v0.x)); atomicAdd(f0 + 1, bf2f(v0.y));
        atomicAdd(f0 + 2, bf2f(v0.z)); atomicAdd(f0 + 3, bf2f(v0.w));
      }
      asm volatile("s_waitcnt lgkmcnt(0)" ::: "memory");  // atomics visible
      // convert facc -> z segment (bf16, divide by count)
#pragma unroll
      for (int t = 0; t < 16 * FQ / 64; ++t) {
        int idx = t * 64 + lane;
        float4 v = ((float4*)fa)[idx];
        int n_off = idx / FQ;
        int kk = (idx % FQ) * 4;
        float iv = icw[n_off];
        ushort4 o;
        o.x = f2bf(v.x * iv); o.y = f2bf(v.y * iv);
        o.z = f2bf(v.z * iv); o.w = f2bf(v.w * iv);
        *(ushort4*)(&zw[n_off * ZSTR + e * KIN + kk]) = o;
      }
    }
    // ---- MFMA: 16 nodes x 64 out cols, K = KCAT ----
    floatx4 acc[4];
#pragma unroll
    for (int ct = 0; ct < 4; ++ct) {
      float bv = bias[ct * 16 + cl];
      acc[ct] = (floatx4){bv, bv, bv, bv};
    }
#pragma unroll
    for (int kc = 0; kc < KCH; ++kc) {
      short8 a = *(const short8*)(&zw[cl * ZSTR + kc * 32 + quad * 8]);
#pragma unroll
      for (int ct = 0; ct < 4; ++ct) {
        short8 b = *(const short8*)(wsw + ((size_t)(kc * 4 + ct) * 64 + lane) * 8);
        acc[ct] = __builtin_amdgcn_mfma_f32_16x16x32_bf16(a, b, acc[ct], 0, 0, 0);
      }
    }
    // ---- epilogue ----
    if (OMODE == 2) {
      float p[4] = {0.f, 0.f, 0.f, 0.f};
#pragma unroll
      for (int ct = 0; ct < 4; ++ct) {
        float w = linW[ct * 16 + cl];
#pragma unroll
        for (int r = 0; r < 4; ++r) {
          float v = acc[ct][r];
          v = v > 0.f ? v : 0.f;
          p[r] += v * w;
        }
      }
#pragma unroll
      for (int off = 1; off < 16; off <<= 1) {
#pragma unroll
        for (int r = 0; r < 4; ++r) p[r] += __shfl_xor(p[r], off, 64);
      }
      if (cl == 0) {
        float lb = linb[0], al = pa[0];
        float* o = (float*)hOut;
#pragma unroll
        for (int r = 0; r < 4; ++r) {
          int n = nb + quad * 4 + r;
          float v = p[r] + lb;
          o[n] = v >= 0.f ? v : al * v;
        }
      }
    } else {
#pragma unroll
      for (int ct = 0; ct < 4; ++ct)
#pragma unroll
        for (int r = 0; r < 4; ++r) {
          int n = nb + quad * 4 + r;
          float v = acc[ct][r];
          v = v > 0.f ? v : 0.f;
          if (OMODE == 1)
            ((float*)hOut)[(size_t)n * 64 + ct * 16 + cl] = v;
          else
            ((unsigned short*)hOut)[(size_t)n * 64 + ct * 16 + cl] = f2bf(v);
        }
    }
  }
}

extern "C" void kernel_launch(void* const* d_in, const int* in_sizes, int n_in,
                              void* d_out, int out_size, void* d_ws,
                              size_t ws_size, hipStream_t stream) {
  const float* x_pf = (const float*)d_in[0];
  const float* x_gw = (const float*)d_in[1];
  const float* x_sw = (const float*)d_in[2];
  const float* W1l = (const float*)d_in[3];
  const float* b1l = (const float*)d_in[4];
  const float* W1r = (const float*)d_in[5];
  const float* W2l = (const float*)d_in[6];
  const float* b2l = (const float*)d_in[7];
  const float* W2r = (const float*)d_in[8];
  const float* linW = (const float*)d_in[9];
  const float* linb = (const float*)d_in[10];
  const float* pa = (const float*)d_in[11];
  const int* e0 = (const int*)d_in[12];  // pf->gw
  const int* e1 = (const int*)d_in[13];  // gw->pf
  const int* e2 = (const int*)d_in[14];  // pf->sw
  const int* e3 = (const int*)d_in[15];  // sw->pf
  const int* e4 = (const int*)d_in[16];  // sw->gw
  const int* e5 = (const int*)d_in[17];  // gw->sw
  const int* e6 = (const int*)d_in[18];  // gw->gw
  float* out = (float*)d_out;

  char* w = (char*)d_ws;
  size_t off = 0;
  auto alloc = [&](size_t bytes) -> void* {
    void* p = w + off;
    off += bytes;
    off = (off + 255) & ~(size_t)255;
    return p;
  };
  int* cnt = (int*)alloc((size_t)L_CNT * 4);
  int* Sarr = (int*)alloc((size_t)(L_CNT + 1) * 4);
  int* loc = (int*)alloc((size_t)7 * EPT * 4);
  int* col = (int*)alloc((size_t)7 * EPT * 4);
  int* bsum = (int*)alloc(1280 * 4);
  int* bpre = (int*)alloc(1280 * 4);
  unsigned short* xb_pf = (unsigned short*)alloc((size_t)N_PF * 32 * 2);
  unsigned short* xb_gw = (unsigned short*)alloc((size_t)N_GW * 32 * 2);
  unsigned short* xb_sw = (unsigned short*)alloc((size_t)N_SW * 32 * 2);
  unsigned short* h1_pf = (unsigned short*)alloc((size_t)N_PF * 64 * 2);
  unsigned short* h1_gw = (unsigned short*)alloc((size_t)N_GW * 64 * 2);
  unsigned short* h1_sw = (unsigned short*)alloc((size_t)N_SW * 64 * 2);
  unsigned short* w1gw = (unsigned short*)alloc(128 * 64 * 2);
  unsigned short* w1pf = (unsigned short*)alloc(96 * 64 * 2);
  unsigned short* w1sw = (unsigned short*)alloc(96 * 64 * 2);
  unsigned short* w2gw = (unsigned short*)alloc(256 * 64 * 2);
  unsigned short* w2pf = (unsigned short*)alloc(192 * 64 * 2);
  unsigned short* w2sw = (unsigned short*)alloc(192 * 64 * 2);
  float* bs1gw = (float*)alloc(64 * 4);
  float* bs1pf = (float*)alloc(64 * 4);
  float* bs1sw = (float*)alloc(64 * 4);
  float* bs2gw = (float*)alloc(64 * 4);
  float* bs2pf = (float*)alloc(64 * 4);
  float* bs2sw = (float*)alloc(64 * 4);

  // input casts
  k_cast<<<(N_PF * 8 + 255) / 256, 256, 0, stream>>>((const float4*)x_pf,
                                                     (ushort4*)xb_pf, N_PF * 8);
  k_cast<<<(N_GW * 8 + 255) / 256, 256, 0, stream>>>((const float4*)x_gw,
                                                     (ushort4*)xb_gw, N_GW * 8);
  k_cast<<<(N_SW * 8 + 255) / 256, 256, 0, stream>>>((const float4*)x_sw,
                                                     (ushort4*)xb_sw, N_SW * 8);

  // CSR build (shared by both layers)
  hipMemsetAsync(cnt, 0, (size_t)L_CNT * 4, stream);
  int ebl = (7 * EPT + 255) / 256;
  k_count<<<ebl, 256, 0, stream>>>(e0, e1, e2, e3, e4, e5, e6, cnt, loc);
  k_scan1<<<NBLK, 256, 0, stream>>>(cnt, bsum);
  k_scan2<<<1, 256, 0, stream>>>(bsum, bpre);
  k_scan3<<<NBLK, 256, 0, stream>>>(cnt, bpre, Sarr);
  k_fill<<<ebl, 256, 0, stream>>>(e0, e1, e2, e3, e4, e5, e6, Sarr, loc, col);

  // weight prep
  k_prep<32, 3><<<(128 * 64 + 64 + 255) / 256, 256, 0, stream>>>(
      W1l, W1r, b1l, 0, 4, 6, 7, w1gw, bs1gw);
  k_prep<32, 2><<<(96 * 64 + 64 + 255) / 256, 256, 0, stream>>>(
      W1l, W1r, b1l, 1, 3, 0, 9, w1pf, bs1pf);
  k_prep<32, 2><<<(96 * 64 + 64 + 255) / 256, 256, 0, stream>>>(
      W1l, W1r, b1l, 2, 5, 0, 8, w1sw, bs1sw);
  k_prep<64, 3><<<(256 * 64 + 64 + 255) / 256, 256, 0, stream>>>(
      W2l, W2r, b2l, 0, 4, 6, 7, w2gw, bs2gw);
  k_prep<64, 2><<<(192 * 64 + 64 + 255) / 256, 256, 0, stream>>>(
      W2l, W2r, b2l, 1, 3, 0, 9, w2pf, bs2pf);
  k_prep<64, 2><<<(192 * 64 + 64 + 255) / 256, 256, 0, stream>>>(
      W2l, W2r, b2l, 2, 5, 0, 8, w2sw, bs2sw);

  // layer 1 (KIN=32) -> bf16 h1   (4 blocks/CU fit: LDS ~25.6/21.5 KB)
  k_layer<32, 3, 0><<<1024, 256, 0, stream>>>(
      Sarr, col, xb_pf, xb_sw, xb_gw, 0, 480000, 840000, xb_gw, w1gw, bs1gw,
      h1_gw, nullptr, nullptr, nullptr, N_GW);
  k_layer<32, 2, 0><<<1024, 256, 0, stream>>>(
      Sarr, col, xb_gw, xb_sw, (const unsigned short*)nullptr, 300000, 420000,
      0, xb_pf, w1pf, bs1pf, h1_pf, nullptr, nullptr, nullptr, N_PF);
  k_layer<32, 2, 0><<<1024, 256, 0, stream>>>(
      Sarr, col, xb_pf, xb_gw, (const unsigned short*)nullptr, 360000, 780000,
      0, xb_sw, w1sw, bs1sw, h1_sw, nullptr, nullptr, nullptr, N_SW);

  // layer 2 (KIN=64): 3 blocks/CU (LDS ~50/42 KB) -> grid 768
  k_layer<64, 3, 2><<<768, 256, 0, stream>>>(
      Sarr, col, h1_pf, h1_sw, h1_gw, 0, 480000, 840000, h1_gw, w2gw, bs2gw,
      out, linW, linb, pa, N_GW);
  k_layer<64, 2, 1><<<768, 256, 0, stream>>>(
      Sarr, col, h1_gw, h1_sw, (const unsigned short*)nullptr, 300000, 420000,
      0, h1_pf, w2pf, bs2pf, out + 360000, nullptr, nullptr, nullptr, N_PF);
  k_layer<64, 2, 2><<<768, 256, 0, stream>>>(
      Sarr, col, h1_pf, h1_gw, (const unsigned short*)nullptr, 360000, 780000,
      0, h1_sw, w2sw, bs2sw, out + N_GW, linW, linb, pa, N_SW);
}

// Round 5
// 1193.674 us; speedup vs baseline: 3.6276x; 3.6276x over previous
//
#include <hip/hip_runtime.h>

typedef __attribute__((ext_vector_type(8))) short short8;
typedef __attribute__((ext_vector_type(4))) float floatx4;

#define N_PF 60000
#define N_GW 300000
#define N_SW 60000
#define EPT 1000000          // edges per (non-self) edge type
#define TOTE 7000000
#define L_CNT 1140000        // concat of 7 per-dst count arrays
#define NBLK 1114            // ceil(L_CNT/1024)
#define SRC_MASK 0x7FFFFFF   // low 27 bits = src id
#define POS_MASK 0x7FFFFF    // low 23 bits = CSR position (7M < 2^23)
#define FB 8                 // fill buckets
#define BSPAN 875000         // TOTE / FB
#define FSLICE 2048
#define NSLICE ((TOTE + FSLICE - 1) / FSLICE)

__device__ __forceinline__ unsigned short f2bf(float f) {
  unsigned u = __float_as_uint(f);
  u = (u + 0x7FFF + ((u >> 16) & 1)) >> 16;
  return (unsigned short)u;
}
__device__ __forceinline__ float bf2f(unsigned short u) {
  return __uint_as_float((unsigned)u << 16);
}
__device__ __forceinline__ void acc8(float* a, short8 v) {
#pragma unroll
  for (int k = 0; k < 8; ++k) a[k] += bf2f((unsigned short)v[k]);
}

__device__ __forceinline__ int cnt_base(int et) {
  switch (et) {
    case 0: return 0;
    case 1: return 300000;
    case 2: return 360000;
    case 3: return 420000;
    case 4: return 480000;
    case 5: return 780000;
    default: return 840000;
  }
}

// ---------------- input cast f32 -> bf16 ----------------
__global__ __launch_bounds__(256) void k_cast(const float4* __restrict__ x,
                                              ushort4* __restrict__ xb, int n4) {
  int i = blockIdx.x * 256 + threadIdx.x;
  if (i < n4) {
    float4 v = x[i];
    ushort4 o;
    o.x = f2bf(v.x); o.y = f2bf(v.y); o.z = f2bf(v.z); o.w = f2bf(v.w);
    xb[i] = o;
  }
}

// ---------------- CSR build ----------------
__global__ __launch_bounds__(256) void k_count(
    const int* e0, const int* e1, const int* e2, const int* e3,
    const int* e4, const int* e5, const int* e6, int* __restrict__ cnt,
    int* __restrict__ loc) {
  int gid = blockIdx.x * 256 + threadIdx.x;
  if (gid >= TOTE) return;
  int et = gid / EPT;
  int i = gid - et * EPT;
  const int* ei;
  switch (et) {
    case 0: ei = e0; break; case 1: ei = e1; break; case 2: ei = e2; break;
    case 3: ei = e3; break; case 4: ei = e4; break; case 5: ei = e5; break;
    default: ei = e6; break;
  }
  int dst = ei[EPT + i];
  loc[gid] = atomicAdd(&cnt[cnt_base(et) + dst], 1);
}

__global__ __launch_bounds__(256) void k_scan1(const int* __restrict__ cnt,
                                               int* __restrict__ bsum) {
  __shared__ int sh[4];
  int base = blockIdx.x * 1024 + threadIdx.x * 4;
  int s = 0;
#pragma unroll
  for (int u = 0; u < 4; ++u) { int i = base + u; if (i < L_CNT) s += cnt[i]; }
  for (int off = 1; off < 64; off <<= 1) s += __shfl_xor(s, off, 64);
  int lane = threadIdx.x & 63, w = threadIdx.x >> 6;
  if (lane == 0) sh[w] = s;
  __syncthreads();
  if (threadIdx.x == 0) bsum[blockIdx.x] = sh[0] + sh[1] + sh[2] + sh[3];
}

__global__ __launch_bounds__(256) void k_scan2(const int* __restrict__ bsum,
                                               int* __restrict__ bpre) {
  __shared__ int sh[256];
  int carry = 0;
  for (int base = 0; base < NBLK; base += 256) {
    int idx = base + threadIdx.x;
    int v = (idx < NBLK) ? bsum[idx] : 0;
    sh[threadIdx.x] = v;
    __syncthreads();
    for (int off = 1; off < 256; off <<= 1) {
      int t = (threadIdx.x >= off) ? sh[threadIdx.x - off] : 0;
      __syncthreads();
      sh[threadIdx.x] += t;
      __syncthreads();
    }
    if (idx < NBLK) bpre[idx] = carry + sh[threadIdx.x] - v;  // exclusive
    carry += sh[255];
    __syncthreads();
  }
}

__global__ __launch_bounds__(256) void k_scan3(const int* __restrict__ cnt,
                                               const int* __restrict__ bpre,
                                               int* __restrict__ Sarr) {
  __shared__ int wt[4];
  int lane = threadIdx.x & 63, w = threadIdx.x >> 6;
  int base = blockIdx.x * 1024 + threadIdx.x * 4;
  int v[4]; int ts = 0;
#pragma unroll
  for (int u = 0; u < 4; ++u) {
    int i = base + u;
    v[u] = (i < L_CNT) ? cnt[i] : 0;
    ts += v[u];
  }
  int x = ts;
  for (int off = 1; off < 64; off <<= 1) {
    int t = __shfl_up(x, off, 64);
    if (lane >= off) x += t;
  }
  int wexcl = x - ts;
  if (lane == 63) wt[w] = x;
  __syncthreads();
  int wpre = 0;
#pragma unroll
  for (int u = 0; u < 4; ++u) if (u < w) wpre += wt[u];
  int run = bpre[blockIdx.x] + wpre + wexcl;
#pragma unroll
  for (int u = 0; u < 4; ++u) {
    int i = base + u;
    if (i < L_CNT) Sarr[i] = run;
    run += v[u];
    if (i == L_CNT - 1) Sarr[L_CNT] = run;  // sentinel = total (7M)
  }
}

// pos[gid] = CSR position | (dst&15)<<23  (coalesced write; one Sarr gather)
__global__ __launch_bounds__(256) void k_pos(
    const int* e0, const int* e1, const int* e2, const int* e3,
    const int* e4, const int* e5, const int* e6,
    const int* __restrict__ Sarr, const int* __restrict__ loc,
    unsigned* __restrict__ pos) {
  int gid = blockIdx.x * 256 + threadIdx.x;
  if (gid >= TOTE) return;
  int et = gid / EPT;
  int i = gid - et * EPT;
  const int* ei;
  switch (et) {
    case 0: ei = e0; break; case 1: ei = e1; break; case 2: ei = e2; break;
    case 3: ei = e3; break; case 4: ei = e4; break; case 5: ei = e5; break;
    default: ei = e6; break;
  }
  int dst = ei[EPT + i];
  unsigned p = (unsigned)(Sarr[cnt_base(et) + dst] + loc[gid]);
  pos[gid] = p | ((unsigned)(dst & 15) << 23);
}

// bucketed fill: bucket = blockIdx&7 (rides XCD round-robin); writes confined
// to a 3.5MB L2-resident col window -> write-combining instead of 64B/line
__global__ __launch_bounds__(256) void k_fill_b(
    const int* e0, const int* e1, const int* e2, const int* e3,
    const int* e4, const int* e5, const int* e6,
    const unsigned* __restrict__ pos, int* __restrict__ col) {
  int bk = blockIdx.x & (FB - 1);
  int slice = blockIdx.x >> 3;
  unsigned lo = (unsigned)bk * BSPAN, hi = lo + BSPAN;
  int base = slice * FSLICE;
#pragma unroll
  for (int u = 0; u < FSLICE / 256; ++u) {
    int gid = base + u * 256 + threadIdx.x;
    if (gid >= TOTE) break;
    unsigned pp = pos[gid];
    unsigned p = pp & POS_MASK;
    if (p >= lo && p < hi) {
      int et = gid / EPT;
      int i = gid - et * EPT;
      const int* ei;
      switch (et) {
        case 0: ei = e0; break; case 1: ei = e1; break; case 2: ei = e2; break;
        case 3: ei = e3; break; case 4: ei = e4; break; case 5: ei = e5; break;
        default: ei = e6; break;
      }
      col[p] = ei[i] | (int)((pp >> 23) << 27);
    }
  }
}

// ---------------- weight prep (fold + swizzle -> bf16) ----------------
template <int KIN, int NE>
__global__ __launch_bounds__(256) void k_prep(
    const float* __restrict__ Wl, const float* __restrict__ Wr,
    const float* __restrict__ bl, int e0, int e1, int e2, int es,
    unsigned short* __restrict__ wsw, float* __restrict__ bias) {
  constexpr int KCAT = (NE + 1) * KIN;
  int idx = blockIdx.x * 256 + threadIdx.x;
  if (idx < KCAT * 64) {
    int j = idx & 7, lane = (idx >> 3) & 63, t = idx >> 9;
    int ct = t & 3, kc = t >> 2;
    int k = kc * 32 + ((lane >> 4) << 3) + j;
    int c = ct * 16 + (lane & 15);
    int seg = k / KIN, kk = k - seg * KIN;
    float v;
    if (seg < NE) {
      int e = (seg == 0) ? e0 : (seg == 1) ? e1 : e2;
      v = Wl[((size_t)e * 64 + c) * KIN + kk];
    } else {
      v = Wl[((size_t)es * 64 + c) * KIN + kk] +
          Wr[((size_t)es * 64 + c) * KIN + kk] +
          Wr[((size_t)e0 * 64 + c) * KIN + kk] +
          Wr[((size_t)e1 * 64 + c) * KIN + kk];
      if (NE == 3) v += Wr[((size_t)e2 * 64 + c) * KIN + kk];
    }
    wsw[idx] = f2bf(v);
  } else if (idx < KCAT * 64 + 64) {
    int c = idx - KCAT * 64;
    float v = bl[e0 * 64 + c] + bl[e1 * 64 + c] + bl[es * 64 + c];
    if (NE == 3) v += bl[e2 * 64 + c];
    bias[c] = v;
  }
}

// ------- fused gather(mean,bf16) + MFMA + bias + ReLU [+lin] -------
// Register-accumulation chains (R3 style), but 16B short8 loads:
// LPR = KIN/8 lanes per row -> G = 64/LPR concurrent chains per wave.
// OMODE: 0 = store bf16 h, 1 = store f32 h, 2 = fused linear+PReLU -> f32 out
template <int KIN, int NE, int OMODE>
__global__ __launch_bounds__(256) void k_layer(
    const int* __restrict__ Sarr, const int* __restrict__ col,
    const unsigned short* __restrict__ s0, const unsigned short* __restrict__ s1,
    const unsigned short* __restrict__ s2, int b0, int b1, int b2,
    const unsigned short* __restrict__ xD,
    const unsigned short* __restrict__ wsw, const float* __restrict__ bias,
    void* __restrict__ hOut, const float* __restrict__ linW,
    const float* __restrict__ linb, const float* __restrict__ pa, int Ndst) {
  constexpr int KCAT = (NE + 1) * KIN;
  constexpr int KCH = KCAT / 32;
  constexpr int ZSTR = KCAT + 8;   // multiple of 8 ushorts -> 16B-aligned rows
  constexpr int LPR = KIN / 8;     // lanes per feature row (8 or 4)
  constexpr int G = 64 / LPR;      // concurrent chains per wave (8 or 16)
  __shared__ unsigned short z[4 * 16 * ZSTR];
  const int lane = threadIdx.x & 63;
  unsigned short* zw = &z[(threadIdx.x >> 6) * 16 * ZSTR];
  const int wid = (blockIdx.x * 256 + threadIdx.x) >> 6;
  const int nw = (gridDim.x * 256) >> 6;
  const unsigned short* srcs[3] = {s0, s1, s2};
  const int bases[3] = {b0, b1, b2};
  const int cl = lane & 15, quad = lane >> 4;
  const int g = lane / LPR;        // chain/group id
  const int c = lane % LPR;        // 16B chunk within row

  for (int nb = wid * 16; nb < Ndst; nb += nw * 16) {  // Ndst % 16 == 0
    // ---- self rows (bf16 passthrough) ----
#pragma unroll
    for (int i0 = 0; i0 < 16; i0 += G) {
      int n = nb + i0 + g;
      *(short8*)(&zw[(i0 + g) * ZSTR + NE * KIN + c * 8]) =
          *(const short8*)(xD + (size_t)n * KIN + c * 8);
    }
    // ---- per-(node, etype) chains; G concurrent per wave ----
#pragma unroll
    for (int i0 = 0; i0 < 16; i0 += G) {
      int n = nb + i0 + g;
      unsigned short* zr = &zw[(i0 + g) * ZSTR];
#pragma unroll
      for (int e = 0; e < NE; ++e) {
        int s = Sarr[bases[e] + n];
        int t = Sarr[bases[e] + n + 1];  // sentinel-safe
        float a0[8] = {0, 0, 0, 0, 0, 0, 0, 0};
        float a1[8] = {0, 0, 0, 0, 0, 0, 0, 0};
        int j = s;
        for (; j + 1 < t; j += 2) {
          int r0 = col[j] & SRC_MASK, r1 = col[j + 1] & SRC_MASK;
          short8 v0 = *(const short8*)(srcs[e] + (size_t)r0 * KIN + c * 8);
          short8 v1 = *(const short8*)(srcs[e] + (size_t)r1 * KIN + c * 8);
          acc8(a0, v0);
          acc8(a1, v1);
        }
        if (j < t) {
          int r0 = col[j] & SRC_MASK;
          short8 v0 = *(const short8*)(srcs[e] + (size_t)r0 * KIN + c * 8);
          acc8(a0, v0);
        }
        int cv = t - s;
        if (cv < 1) cv = 1;
        float inv = 1.0f / (float)cv;
        short8 o;
#pragma unroll
        for (int k = 0; k < 8; ++k)
          o[k] = (short)f2bf((a0[k] + a1[k]) * inv);
        *(short8*)(&zr[e * KIN + c * 8]) = o;
      }
    }
    // ---- MFMA: 16 nodes x 64 out cols, K = KCAT ----
    floatx4 acc[4];
#pragma unroll
    for (int ct = 0; ct < 4; ++ct) {
      float bv = bias[ct * 16 + cl];
      acc[ct] = (floatx4){bv, bv, bv, bv};
    }
#pragma unroll
    for (int kc = 0; kc < KCH; ++kc) {
      short8 a = *(const short8*)(&zw[cl * ZSTR + kc * 32 + quad * 8]);
#pragma unroll
      for (int ct = 0; ct < 4; ++ct) {
        short8 b = *(const short8*)(wsw + ((size_t)(kc * 4 + ct) * 64 + lane) * 8);
        acc[ct] = __builtin_amdgcn_mfma_f32_16x16x32_bf16(a, b, acc[ct], 0, 0, 0);
      }
    }
    // ---- epilogue ----
    if (OMODE == 2) {
      float p[4] = {0.f, 0.f, 0.f, 0.f};
#pragma unroll
      for (int ct = 0; ct < 4; ++ct) {
        float w = linW[ct * 16 + cl];
#pragma unroll
        for (int r = 0; r < 4; ++r) {
          float v = acc[ct][r];
          v = v > 0.f ? v : 0.f;
          p[r] += v * w;
        }
      }
#pragma unroll
      for (int off = 1; off < 16; off <<= 1) {
#pragma unroll
        for (int r = 0; r < 4; ++r) p[r] += __shfl_xor(p[r], off, 64);
      }
      if (cl == 0) {
        float lb = linb[0], al = pa[0];
        float* o = (float*)hOut;
#pragma unroll
        for (int r = 0; r < 4; ++r) {
          int n = nb + quad * 4 + r;
          float v = p[r] + lb;
          o[n] = v >= 0.f ? v : al * v;
        }
      }
    } else {
#pragma unroll
      for (int ct = 0; ct < 4; ++ct)
#pragma unroll
        for (int r = 0; r < 4; ++r) {
          int n = nb + quad * 4 + r;
          float v = acc[ct][r];
          v = v > 0.f ? v : 0.f;
          if (OMODE == 1)
            ((float*)hOut)[(size_t)n * 64 + ct * 16 + cl] = v;
          else
            ((unsigned short*)hOut)[(size_t)n * 64 + ct * 16 + cl] = f2bf(v);
        }
    }
  }
}

extern "C" void kernel_launch(void* const* d_in, const int* in_sizes, int n_in,
                              void* d_out, int out_size, void* d_ws,
                              size_t ws_size, hipStream_t stream) {
  const float* x_pf = (const float*)d_in[0];
  const float* x_gw = (const float*)d_in[1];
  const float* x_sw = (const float*)d_in[2];
  const float* W1l = (const float*)d_in[3];
  const float* b1l = (const float*)d_in[4];
  const float* W1r = (const float*)d_in[5];
  const float* W2l = (const float*)d_in[6];
  const float* b2l = (const float*)d_in[7];
  const float* W2r = (const float*)d_in[8];
  const float* linW = (const float*)d_in[9];
  const float* linb = (const float*)d_in[10];
  const float* pa = (const float*)d_in[11];
  const int* e0 = (const int*)d_in[12];  // pf->gw
  const int* e1 = (const int*)d_in[13];  // gw->pf
  const int* e2 = (const int*)d_in[14];  // pf->sw
  const int* e3 = (const int*)d_in[15];  // sw->pf
  const int* e4 = (const int*)d_in[16];  // sw->gw
  const int* e5 = (const int*)d_in[17];  // gw->sw
  const int* e6 = (const int*)d_in[18];  // gw->gw
  float* out = (float*)d_out;

  char* w = (char*)d_ws;
  size_t off = 0;
  auto alloc = [&](size_t bytes) -> void* {
    void* p = w + off;
    off += bytes;
    off = (off + 255) & ~(size_t)255;
    return p;
  };
  int* cnt = (int*)alloc((size_t)L_CNT * 4);
  int* Sarr = (int*)alloc((size_t)(L_CNT + 1) * 4);
  int* loc = (int*)alloc((size_t)TOTE * 4);
  unsigned* pos = (unsigned*)alloc((size_t)TOTE * 4);
  int* col = (int*)alloc((size_t)TOTE * 4);
  int* bsum = (int*)alloc(1280 * 4);
  int* bpre = (int*)alloc(1280 * 4);
  unsigned short* xb_pf = (unsigned short*)alloc((size_t)N_PF * 32 * 2);
  unsigned short* xb_gw = (unsigned short*)alloc((size_t)N_GW * 32 * 2);
  unsigned short* xb_sw = (unsigned short*)alloc((size_t)N_SW * 32 * 2);
  unsigned short* h1_pf = (unsigned short*)alloc((size_t)N_PF * 64 * 2);
  unsigned short* h1_gw = (unsigned short*)alloc((size_t)N_GW * 64 * 2);
  unsigned short* h1_sw = (unsigned short*)alloc((size_t)N_SW * 64 * 2);
  unsigned short* w1gw = (unsigned short*)alloc(128 * 64 * 2);
  unsigned short* w1pf = (unsigned short*)alloc(96 * 64 * 2);
  unsigned short* w1sw = (unsigned short*)alloc(96 * 64 * 2);
  unsigned short* w2gw = (unsigned short*)alloc(256 * 64 * 2);
  unsigned short* w2pf = (unsigned short*)alloc(192 * 64 * 2);
  unsigned short* w2sw = (unsigned short*)alloc(192 * 64 * 2);
  float* bs1gw = (float*)alloc(64 * 4);
  float* bs1pf = (float*)alloc(64 * 4);
  float* bs1sw = (float*)alloc(64 * 4);
  float* bs2gw = (float*)alloc(64 * 4);
  float* bs2pf = (float*)alloc(64 * 4);
  float* bs2sw = (float*)alloc(64 * 4);

  // input casts
  k_cast<<<(N_PF * 8 + 255) / 256, 256, 0, stream>>>((const float4*)x_pf,
                                                     (ushort4*)xb_pf, N_PF * 8);
  k_cast<<<(N_GW * 8 + 255) / 256, 256, 0, stream>>>((const float4*)x_gw,
                                                     (ushort4*)xb_gw, N_GW * 8);
  k_cast<<<(N_SW * 8 + 255) / 256, 256, 0, stream>>>((const float4*)x_sw,
                                                     (ushort4*)xb_sw, N_SW * 8);

  // CSR build (shared by both layers)
  hipMemsetAsync(cnt, 0, (size_t)L_CNT * 4, stream);
  int ebl = (TOTE + 255) / 256;
  k_count<<<ebl, 256, 0, stream>>>(e0, e1, e2, e3, e4, e5, e6, cnt, loc);
  k_scan1<<<NBLK, 256, 0, stream>>>(cnt, bsum);
  k_scan2<<<1, 256, 0, stream>>>(bsum, bpre);
  k_scan3<<<NBLK, 256, 0, stream>>>(cnt, bpre, Sarr);
  k_pos<<<ebl, 256, 0, stream>>>(e0, e1, e2, e3, e4, e5, e6, Sarr, loc, pos);
  k_fill_b<<<NSLICE * FB, 256, 0, stream>>>(e0, e1, e2, e3, e4, e5, e6, pos,
                                            col);

  // weight prep
  k_prep<32, 3><<<(128 * 64 + 64 + 255) / 256, 256, 0, stream>>>(
      W1l, W1r, b1l, 0, 4, 6, 7, w1gw, bs1gw);
  k_prep<32, 2><<<(96 * 64 + 64 + 255) / 256, 256, 0, stream>>>(
      W1l, W1r, b1l, 1, 3, 0, 9, w1pf, bs1pf);
  k_prep<32, 2><<<(96 * 64 + 64 + 255) / 256, 256, 0, stream>>>(
      W1l, W1r, b1l, 2, 5, 0, 8, w1sw, bs1sw);
  k_prep<64, 3><<<(256 * 64 + 64 + 255) / 256, 256, 0, stream>>>(
      W2l, W2r, b2l, 0, 4, 6, 7, w2gw, bs2gw);
  k_prep<64, 2><<<(192 * 64 + 64 + 255) / 256, 256, 0, stream>>>(
      W2l, W2r, b2l, 1, 3, 0, 9, w2pf, bs2pf);
  k_prep<64, 2><<<(192 * 64 + 64 + 255) / 256, 256, 0, stream>>>(
      W2l, W2r, b2l, 2, 5, 0, 8, w2sw, bs2sw);

  // layer 1 (KIN=32, G=16) -> bf16 h1
  k_layer<32, 3, 0><<<1024, 256, 0, stream>>>(
      Sarr, col, xb_pf, xb_sw, xb_gw, 0, 480000, 840000, xb_gw, w1gw, bs1gw,
      h1_gw, nullptr, nullptr, nullptr, N_GW);
  k_layer<32, 2, 0><<<1024, 256, 0, stream>>>(
      Sarr, col, xb_gw, xb_sw, (const unsigned short*)nullptr, 300000, 420000,
      0, xb_pf, w1pf, bs1pf, h1_pf, nullptr, nullptr, nullptr, N_PF);
  k_layer<32, 2, 0><<<1024, 256, 0, stream>>>(
      Sarr, col, xb_pf, xb_gw, (const unsigned short*)nullptr, 360000, 780000,
      0, xb_sw, w1sw, bs1sw, h1_sw, nullptr, nullptr, nullptr, N_SW);

  // layer 2 (KIN=64, G=8): gw/sw fuse linear+PReLU; pf -> f32 h_pf out
  k_layer<64, 3, 2><<<1024, 256, 0, stream>>>(
      Sarr, col, h1_pf, h1_sw, h1_gw, 0, 480000, 840000, h1_gw, w2gw, bs2gw,
      out, linW, linb, pa, N_GW);
  k_layer<64, 2, 1><<<1024, 256, 0, stream>>>(
      Sarr, col, h1_gw, h1_sw, (const unsigned short*)nullptr, 300000, 420000,
      0, h1_pf, w2pf, bs2pf, out + 360000, nullptr, nullptr, nullptr, N_PF);
  k_layer<64, 2, 2><<<1024, 256, 0, stream>>>(
      Sarr, col, h1_pf, h1_gw, (const unsigned short*)nullptr, 360000, 780000,
      0, h1_sw, w2sw, bs2sw, out + N_GW, linW, linb, pa, N_SW);
}